// Round 1
// baseline (781.019 us; speedup 1.0000x reference)
//
#include <hip/hip_runtime.h>

#define NUM_USERS 80000
#define NUM_ITEMS 40000
#define NUM_NODES 120000
#define DIM 64
#define ALPHA_C 0.8f

// ---------------------------------------------------------------------------
// K1: softmax over theta (6 elements) -> theta_w
// ---------------------------------------------------------------------------
__global__ void k_softmax_theta(const float* __restrict__ theta,
                                float* __restrict__ theta_w) {
    if (threadIdx.x == 0 && blockIdx.x == 0) {
        float m = -1e30f;
        for (int i = 0; i < 6; ++i) m = fmaxf(m, theta[i]);
        float e[6];
        float s = 0.f;
        for (int i = 0; i < 6; ++i) { e[i] = expf(theta[i] - m); s += e[i]; }
        for (int i = 0; i < 6; ++i) theta_w[i] = e[i] / s;
    }
}

// ---------------------------------------------------------------------------
// K2: exp_v[e] = exp(dot(p_counts[e, 0:6], theta_w))
// ---------------------------------------------------------------------------
__global__ void k_expv(const float* __restrict__ p_counts,
                       const float* __restrict__ theta_w,
                       float* __restrict__ exp_v, int E) {
    int i = blockIdx.x * blockDim.x + threadIdx.x;
    if (i >= E) return;
    const float* c = p_counts + (size_t)i * 6;
    float v = c[0] * theta_w[0] + c[1] * theta_w[1] + c[2] * theta_w[2] +
              c[3] * theta_w[3] + c[4] * theta_w[4] + c[5] * theta_w[5];
    exp_v[i] = expf(v);
}

// ---------------------------------------------------------------------------
// K3: CSR row_ptr via lower_bound binary search (rows are sorted: np.unique)
// ---------------------------------------------------------------------------
__global__ void k_row_ptr(const int* __restrict__ rows, int nnz,
                          int* __restrict__ ptr, int n) {
    int r = blockIdx.x * blockDim.x + threadIdx.x;
    if (r > n) return;
    int lo = 0, hi = nnz;
    while (lo < hi) {
        int mid = (lo + hi) >> 1;
        if (rows[mid] < r) lo = mid + 1; else hi = mid;
    }
    ptr[r] = lo;
}

// ---------------------------------------------------------------------------
// Wave-cooperative segment gather:
//   wave = 4 groups x 16 lanes; group g handles edges start+g, start+g+4, ...
//   each lane loads float4 (li = lane & 15 selects the 16B chunk of the row)
//   returns sum over the segment, reduced across groups (valid in all lanes)
// ---------------------------------------------------------------------------
__device__ __forceinline__ float4 seg_gather(const int* __restrict__ col,
                                             const float* __restrict__ val,
                                             int start, int end,
                                             const float* __restrict__ x,
                                             int group, int li) {
    float4 acc = make_float4(0.f, 0.f, 0.f, 0.f);
    for (int e = start + group; e < end; e += 4) {
        int c = col[e];
        float v = val[e];
        float4 xv = *((const float4*)(x + (size_t)c * DIM) + li);
        acc.x = fmaf(v, xv.x, acc.x);
        acc.y = fmaf(v, xv.y, acc.y);
        acc.z = fmaf(v, xv.z, acc.z);
        acc.w = fmaf(v, xv.w, acc.w);
    }
#pragma unroll
    for (int m = 16; m < 64; m <<= 1) {
        acc.x += __shfl_xor(acc.x, m);
        acc.y += __shfl_xor(acc.y, m);
        acc.z += __shfl_xor(acc.z, m);
        acc.w += __shfl_xor(acc.w, m);
    }
    return acc;
}

// ---------------------------------------------------------------------------
// K4: path SpMM with fused row-softmax. One wave per node/row.
//     e0[row] = sum_e (exp_v[e]/row_sum) * all_emb[col[e]]
//     Also initializes the running sum (d_out) with e0.
// ---------------------------------------------------------------------------
__global__ void k_path(const float* __restrict__ user_emb,
                       const float* __restrict__ item_emb,
                       const float* __restrict__ exp_v,
                       const int* __restrict__ rp,
                       const int* __restrict__ cols,
                       float* __restrict__ e0,
                       float* __restrict__ sum_out) {
    int wid = (blockIdx.x * blockDim.x + threadIdx.x) >> 6;
    if (wid >= NUM_NODES) return;
    int lane = threadIdx.x & 63;
    int group = lane >> 4, li = lane & 15;
    int start = rp[wid], end = rp[wid + 1];

    // softmax denominator over the segment
    float s = 0.f;
    for (int e = start + lane; e < end; e += 64) s += exp_v[e];
#pragma unroll
    for (int m = 1; m < 64; m <<= 1) s += __shfl_xor(s, m);
    float inv = 1.0f / (s + 1e-12f);

    float4 acc = make_float4(0.f, 0.f, 0.f, 0.f);
    for (int e = start + group; e < end; e += 4) {
        int c = cols[e];
        float w = exp_v[e] * inv;
        const float* base = (c < NUM_USERS)
                                ? (user_emb + (size_t)c * DIM)
                                : (item_emb + (size_t)(c - NUM_USERS) * DIM);
        float4 xv = ((const float4*)base)[li];
        acc.x = fmaf(w, xv.x, acc.x);
        acc.y = fmaf(w, xv.y, acc.y);
        acc.z = fmaf(w, xv.z, acc.z);
        acc.w = fmaf(w, xv.w, acc.w);
    }
#pragma unroll
    for (int m = 16; m < 64; m <<= 1) {
        acc.x += __shfl_xor(acc.x, m);
        acc.y += __shfl_xor(acc.y, m);
        acc.z += __shfl_xor(acc.z, m);
        acc.w += __shfl_xor(acc.w, m);
    }
    if (lane < 16) {
        ((float4*)(e0 + (size_t)wid * DIM))[li] = acc;
        ((float4*)(sum_out + (size_t)wid * DIM))[li] = acc;
    }
}

// ---------------------------------------------------------------------------
// K5: one propagation layer. One wave per node/row.
//     res = pos_acc + ALPHA * (e_in[row] - neg_acc)
//     sum_io += res ; final layer: sum_io = (sum_io + res) * 0.25
// ---------------------------------------------------------------------------
__global__ void k_layer(const float* __restrict__ e_in,
                        float* __restrict__ e_out,
                        float* __restrict__ sum_io,
                        const int* __restrict__ rp_p,
                        const int* __restrict__ col_p,
                        const float* __restrict__ val_p,
                        const int* __restrict__ rp_n,
                        const int* __restrict__ col_n,
                        const float* __restrict__ val_n,
                        int is_final) {
    int wid = (blockIdx.x * blockDim.x + threadIdx.x) >> 6;
    if (wid >= NUM_NODES) return;
    int lane = threadIdx.x & 63;
    int group = lane >> 4, li = lane & 15;

    float4 ap = seg_gather(col_p, val_p, rp_p[wid], rp_p[wid + 1], e_in, group, li);
    float4 an = seg_gather(col_n, val_n, rp_n[wid], rp_n[wid + 1], e_in, group, li);
    float4 ein = ((const float4*)(e_in + (size_t)wid * DIM))[li];

    float4 res;
    res.x = ap.x + ALPHA_C * (ein.x - an.x);
    res.y = ap.y + ALPHA_C * (ein.y - an.y);
    res.z = ap.z + ALPHA_C * (ein.z - an.z);
    res.w = ap.w + ALPHA_C * (ein.w - an.w);

    if (lane < 16) {
        float4* sp = (float4*)(sum_io + (size_t)wid * DIM) + li;
        float4 s = *sp;
        s.x += res.x; s.y += res.y; s.z += res.z; s.w += res.w;
        if (is_final) { s.x *= 0.25f; s.y *= 0.25f; s.z *= 0.25f; s.w *= 0.25f; }
        *sp = s;
        if (!is_final)
            ((float4*)(e_out + (size_t)wid * DIM))[li] = res;
    }
}

// ---------------------------------------------------------------------------
extern "C" void kernel_launch(void* const* d_in, const int* in_sizes, int n_in,
                              void* d_out, int out_size, void* d_ws, size_t ws_size,
                              hipStream_t stream) {
    const float* user_emb = (const float*)d_in[0];
    const float* item_emb = (const float*)d_in[1];
    const float* theta    = (const float*)d_in[2];
    const int*   pos_row  = (const int*)d_in[3];
    const int*   pos_col  = (const int*)d_in[4];
    const float* pos_val  = (const float*)d_in[5];
    const int*   neg_row  = (const int*)d_in[6];
    const int*   neg_col  = (const int*)d_in[7];
    const float* neg_val  = (const float*)d_in[8];
    const int*   p_row    = (const int*)d_in[9];
    const int*   p_col    = (const int*)d_in[10];
    const float* p_counts = (const float*)d_in[11];
    const int E_pos  = in_sizes[3];
    const int E_neg  = in_sizes[6];
    const int E_path = in_sizes[9];

    // bump allocator over d_ws (256B aligned chunks)
    char* wsb = (char*)d_ws;
    size_t off = 0;
    auto alloc = [&](size_t bytes) -> void* {
        void* p = wsb + off;
        off = (off + bytes + 255) & ~(size_t)255;
        return p;
    };
    float* theta_w = (float*)alloc(6 * sizeof(float));
    float* exp_v   = (float*)alloc((size_t)E_path * sizeof(float));
    int*   rp_pos  = (int*)alloc((size_t)(NUM_NODES + 1) * sizeof(int));
    int*   rp_neg  = (int*)alloc((size_t)(NUM_NODES + 1) * sizeof(int));
    int*   rp_path = (int*)alloc((size_t)(NUM_NODES + 1) * sizeof(int));
    float* eA      = (float*)alloc((size_t)NUM_NODES * DIM * sizeof(float));
    float* eB      = (float*)alloc((size_t)NUM_NODES * DIM * sizeof(float));
    float* sum_io  = (float*)d_out;  // running sum accumulates directly in d_out

    k_softmax_theta<<<1, 64, 0, stream>>>(theta, theta_w);
    k_expv<<<(E_path + 255) / 256, 256, 0, stream>>>(p_counts, theta_w, exp_v, E_path);

    int nb = (NUM_NODES + 1 + 255) / 256;
    k_row_ptr<<<nb, 256, 0, stream>>>(pos_row, E_pos, rp_pos, NUM_NODES);
    k_row_ptr<<<nb, 256, 0, stream>>>(neg_row, E_neg, rp_neg, NUM_NODES);
    k_row_ptr<<<nb, 256, 0, stream>>>(p_row, E_path, rp_path, NUM_NODES);

    // one wave per node, 4 waves (256 threads) per block
    int row_blocks = NUM_NODES / 4;  // 120000 / 4 = 30000

    k_path<<<row_blocks, 256, 0, stream>>>(user_emb, item_emb, exp_v, rp_path,
                                           p_col, eA, sum_io);
    k_layer<<<row_blocks, 256, 0, stream>>>(eA, eB, sum_io,
                                            rp_pos, pos_col, pos_val,
                                            rp_neg, neg_col, neg_val, 0);
    k_layer<<<row_blocks, 256, 0, stream>>>(eB, eA, sum_io,
                                            rp_pos, pos_col, pos_val,
                                            rp_neg, neg_col, neg_val, 0);
    k_layer<<<row_blocks, 256, 0, stream>>>(eA, eB, sum_io,
                                            rp_pos, pos_col, pos_val,
                                            rp_neg, neg_col, neg_val, 1);
}

// Round 2
// 697.942 us; speedup vs baseline: 1.1190x; 1.1190x over previous
//
#include <hip/hip_runtime.h>

#define NUM_USERS 80000
#define NUM_ITEMS 40000
#define NUM_NODES 120000
#define DIM 64
#define ALPHA_C 0.8f

typedef unsigned short u16;

// exact bf16 -> fp32
__device__ __forceinline__ float bf2f(u16 u) {
    union { unsigned int i; float f; } v;
    v.i = ((unsigned int)u) << 16;
    return v.f;
}
// fp32 -> bf16 round-nearest-even
__device__ __forceinline__ u16 f2bf(float f) {
    union { float f; unsigned int i; } v;
    v.f = f;
    unsigned int i = v.i;
    unsigned int r = (i + 0x7FFFu + ((i >> 16) & 1u)) >> 16;
    return (u16)r;
}

// ---------------------------------------------------------------------------
// K1: softmax over theta (6 elements) -> theta_w
// ---------------------------------------------------------------------------
__global__ void k_softmax_theta(const float* __restrict__ theta,
                                float* __restrict__ theta_w) {
    if (threadIdx.x == 0 && blockIdx.x == 0) {
        float m = -1e30f;
        for (int i = 0; i < 6; ++i) m = fmaxf(m, theta[i]);
        float e[6];
        float s = 0.f;
        for (int i = 0; i < 6; ++i) { e[i] = expf(theta[i] - m); s += e[i]; }
        for (int i = 0; i < 6; ++i) theta_w[i] = e[i] / s;
    }
}

// ---------------------------------------------------------------------------
// K2: exp_v[e] = exp(dot(p_counts[e, 0:6], theta_w))
// ---------------------------------------------------------------------------
__global__ void k_expv(const float* __restrict__ p_counts,
                       const float* __restrict__ theta_w,
                       float* __restrict__ exp_v, int E) {
    int i = blockIdx.x * blockDim.x + threadIdx.x;
    if (i >= E) return;
    const float* c = p_counts + (size_t)i * 6;
    float v = c[0] * theta_w[0] + c[1] * theta_w[1] + c[2] * theta_w[2] +
              c[3] * theta_w[3] + c[4] * theta_w[4] + c[5] * theta_w[5];
    exp_v[i] = expf(v);
}

// ---------------------------------------------------------------------------
// K3: all three CSR row_ptr arrays in one launch (rows sorted: np.unique)
// ---------------------------------------------------------------------------
__device__ __forceinline__ void lower_bound_ptr(const int* __restrict__ rows,
                                                int nnz, int r,
                                                int* __restrict__ ptr) {
    int lo = 0, hi = nnz;
    while (lo < hi) {
        int mid = (lo + hi) >> 1;
        if (rows[mid] < r) lo = mid + 1; else hi = mid;
    }
    ptr[r] = lo;
}

__global__ void k_row_ptr3(const int* __restrict__ rows_a, int nnz_a, int* __restrict__ pa,
                           const int* __restrict__ rows_b, int nnz_b, int* __restrict__ pb,
                           const int* __restrict__ rows_c, int nnz_c, int* __restrict__ pc) {
    int t = blockIdx.x * blockDim.x + threadIdx.x;
    int which = t / (NUM_NODES + 1);
    int r = t - which * (NUM_NODES + 1);
    if (which == 0) lower_bound_ptr(rows_a, nnz_a, r, pa);
    else if (which == 1) lower_bound_ptr(rows_b, nnz_b, r, pb);
    else if (which == 2) lower_bound_ptr(rows_c, nnz_c, r, pc);
}

// ---------------------------------------------------------------------------
// K4: convert user_emb || item_emb (fp32) -> bf16 table
// ---------------------------------------------------------------------------
__global__ void k_cvt(const float* __restrict__ user_emb,
                      const float* __restrict__ item_emb,
                      u16* __restrict__ emb16) {
    int i = blockIdx.x * blockDim.x + threadIdx.x;   // handles 4 floats
    size_t f = (size_t)i * 4;
    const size_t UTOT = (size_t)NUM_USERS * DIM;
    const size_t TOT = (size_t)NUM_NODES * DIM;
    if (f >= TOT) return;
    float4 v = (f < UTOT) ? *(const float4*)(user_emb + f)
                          : *(const float4*)(item_emb + (f - UTOT));
    ushort4 o;
    o.x = f2bf(v.x); o.y = f2bf(v.y); o.z = f2bf(v.z); o.w = f2bf(v.w);
    *(ushort4*)(emb16 + f) = o;
}

// ---------------------------------------------------------------------------
// Wave-cooperative segment gather over a bf16 table:
//   wave = 4 groups x 16 lanes; group g handles edges start+g, start+g+4, ...
//   each lane loads ushort4 (8 B = 4 bf16), converts, FMA-accumulates fp32.
//   cross-group __shfl_xor reduce at the end (valid in all lanes).
// ---------------------------------------------------------------------------
__device__ __forceinline__ float4 seg_gather16(const int* __restrict__ col,
                                               const float* __restrict__ val,
                                               int start, int end,
                                               const u16* __restrict__ x,
                                               int group, int li) {
    float4 acc = make_float4(0.f, 0.f, 0.f, 0.f);
    for (int e = start + group; e < end; e += 4) {
        int c = col[e];
        float v = val[e];
        ushort4 xu = *((const ushort4*)(x + (size_t)c * DIM) + li);
        acc.x = fmaf(v, bf2f(xu.x), acc.x);
        acc.y = fmaf(v, bf2f(xu.y), acc.y);
        acc.z = fmaf(v, bf2f(xu.z), acc.z);
        acc.w = fmaf(v, bf2f(xu.w), acc.w);
    }
#pragma unroll
    for (int m = 16; m < 64; m <<= 1) {
        acc.x += __shfl_xor(acc.x, m);
        acc.y += __shfl_xor(acc.y, m);
        acc.z += __shfl_xor(acc.z, m);
        acc.w += __shfl_xor(acc.w, m);
    }
    return acc;
}

// ---------------------------------------------------------------------------
// K5: path SpMM with fused row-softmax. One wave per node/row.
//     e0[row] = sum_e (exp_v[e]/row_sum) * emb16[col[e]]
//     Writes e0 (bf16) and initializes the running sum (d_out, fp32).
// ---------------------------------------------------------------------------
__global__ void k_path(const u16* __restrict__ emb16,
                       const float* __restrict__ exp_v,
                       const int* __restrict__ rp,
                       const int* __restrict__ cols,
                       u16* __restrict__ e0,
                       float* __restrict__ sum_out) {
    int wid = (blockIdx.x * blockDim.x + threadIdx.x) >> 6;
    if (wid >= NUM_NODES) return;
    int lane = threadIdx.x & 63;
    int group = lane >> 4, li = lane & 15;
    int start = rp[wid], end = rp[wid + 1];

    // softmax denominator over the segment
    float s = 0.f;
    for (int e = start + lane; e < end; e += 64) s += exp_v[e];
#pragma unroll
    for (int m = 1; m < 64; m <<= 1) s += __shfl_xor(s, m);
    float inv = 1.0f / (s + 1e-12f);

    float4 acc = make_float4(0.f, 0.f, 0.f, 0.f);
    for (int e = start + group; e < end; e += 4) {
        int c = cols[e];
        float w = exp_v[e] * inv;
        ushort4 xu = *((const ushort4*)(emb16 + (size_t)c * DIM) + li);
        acc.x = fmaf(w, bf2f(xu.x), acc.x);
        acc.y = fmaf(w, bf2f(xu.y), acc.y);
        acc.z = fmaf(w, bf2f(xu.z), acc.z);
        acc.w = fmaf(w, bf2f(xu.w), acc.w);
    }
#pragma unroll
    for (int m = 16; m < 64; m <<= 1) {
        acc.x += __shfl_xor(acc.x, m);
        acc.y += __shfl_xor(acc.y, m);
        acc.z += __shfl_xor(acc.z, m);
        acc.w += __shfl_xor(acc.w, m);
    }
    if (lane < 16) {
        ushort4 o;
        o.x = f2bf(acc.x); o.y = f2bf(acc.y); o.z = f2bf(acc.z); o.w = f2bf(acc.w);
        *((ushort4*)(e0 + (size_t)wid * DIM) + li) = o;
        ((float4*)(sum_out + (size_t)wid * DIM))[li] = acc;
    }
}

// ---------------------------------------------------------------------------
// K6: one propagation layer. One wave per node/row.
//     res = pos_acc + ALPHA * (e_in[row] - neg_acc)
//     sum_io += res ; final layer: sum_io = (sum_io + res) * 0.25
// ---------------------------------------------------------------------------
__global__ void k_layer(const u16* __restrict__ e_in,
                        u16* __restrict__ e_out,
                        float* __restrict__ sum_io,
                        const int* __restrict__ rp_p,
                        const int* __restrict__ col_p,
                        const float* __restrict__ val_p,
                        const int* __restrict__ rp_n,
                        const int* __restrict__ col_n,
                        const float* __restrict__ val_n,
                        int is_final) {
    int wid = (blockIdx.x * blockDim.x + threadIdx.x) >> 6;
    if (wid >= NUM_NODES) return;
    int lane = threadIdx.x & 63;
    int group = lane >> 4, li = lane & 15;

    float4 ap = seg_gather16(col_p, val_p, rp_p[wid], rp_p[wid + 1], e_in, group, li);
    float4 an = seg_gather16(col_n, val_n, rp_n[wid], rp_n[wid + 1], e_in, group, li);

    if (lane < 16) {
        ushort4 eu = *((const ushort4*)(e_in + (size_t)wid * DIM) + li);
        float4 res;
        res.x = ap.x + ALPHA_C * (bf2f(eu.x) - an.x);
        res.y = ap.y + ALPHA_C * (bf2f(eu.y) - an.y);
        res.z = ap.z + ALPHA_C * (bf2f(eu.z) - an.z);
        res.w = ap.w + ALPHA_C * (bf2f(eu.w) - an.w);

        float4* sp = (float4*)(sum_io + (size_t)wid * DIM) + li;
        float4 s = *sp;
        s.x += res.x; s.y += res.y; s.z += res.z; s.w += res.w;
        if (is_final) { s.x *= 0.25f; s.y *= 0.25f; s.z *= 0.25f; s.w *= 0.25f; }
        *sp = s;
        if (!is_final) {
            ushort4 o;
            o.x = f2bf(res.x); o.y = f2bf(res.y); o.z = f2bf(res.z); o.w = f2bf(res.w);
            *((ushort4*)(e_out + (size_t)wid * DIM) + li) = o;
        }
    }
}

// ---------------------------------------------------------------------------
extern "C" void kernel_launch(void* const* d_in, const int* in_sizes, int n_in,
                              void* d_out, int out_size, void* d_ws, size_t ws_size,
                              hipStream_t stream) {
    const float* user_emb = (const float*)d_in[0];
    const float* item_emb = (const float*)d_in[1];
    const float* theta    = (const float*)d_in[2];
    const int*   pos_row  = (const int*)d_in[3];
    const int*   pos_col  = (const int*)d_in[4];
    const float* pos_val  = (const float*)d_in[5];
    const int*   neg_row  = (const int*)d_in[6];
    const int*   neg_col  = (const int*)d_in[7];
    const float* neg_val  = (const float*)d_in[8];
    const int*   p_row    = (const int*)d_in[9];
    const int*   p_col    = (const int*)d_in[10];
    const float* p_counts = (const float*)d_in[11];
    const int E_pos  = in_sizes[3];
    const int E_neg  = in_sizes[6];
    const int E_path = in_sizes[9];

    // bump allocator over d_ws (256B aligned chunks)
    char* wsb = (char*)d_ws;
    size_t off = 0;
    auto alloc = [&](size_t bytes) -> void* {
        void* p = wsb + off;
        off = (off + bytes + 255) & ~(size_t)255;
        return p;
    };
    float* theta_w = (float*)alloc(6 * sizeof(float));
    float* exp_v   = (float*)alloc((size_t)E_path * sizeof(float));
    int*   rp_pos  = (int*)alloc((size_t)(NUM_NODES + 1) * sizeof(int));
    int*   rp_neg  = (int*)alloc((size_t)(NUM_NODES + 1) * sizeof(int));
    int*   rp_path = (int*)alloc((size_t)(NUM_NODES + 1) * sizeof(int));
    u16*   emb16   = (u16*)alloc((size_t)NUM_NODES * DIM * sizeof(u16));
    u16*   eA      = (u16*)alloc((size_t)NUM_NODES * DIM * sizeof(u16));
    u16*   eB      = (u16*)alloc((size_t)NUM_NODES * DIM * sizeof(u16));
    float* sum_io  = (float*)d_out;  // running sum accumulates directly in d_out

    k_softmax_theta<<<1, 64, 0, stream>>>(theta, theta_w);
    k_expv<<<(E_path + 255) / 256, 256, 0, stream>>>(p_counts, theta_w, exp_v, E_path);

    int total_rp = 3 * (NUM_NODES + 1);
    k_row_ptr3<<<(total_rp + 255) / 256, 256, 0, stream>>>(
        pos_row, E_pos, rp_pos, neg_row, E_neg, rp_neg, p_row, E_path, rp_path);

    int cvt_threads = (NUM_NODES * DIM) / 4;
    k_cvt<<<(cvt_threads + 255) / 256, 256, 0, stream>>>(user_emb, item_emb, emb16);

    // one wave per node, 4 waves (256 threads) per block
    int row_blocks = NUM_NODES / 4;  // 120000 / 4 = 30000

    k_path<<<row_blocks, 256, 0, stream>>>(emb16, exp_v, rp_path, p_col, eA, sum_io);
    k_layer<<<row_blocks, 256, 0, stream>>>(eA, eB, sum_io,
                                            rp_pos, pos_col, pos_val,
                                            rp_neg, neg_col, neg_val, 0);
    k_layer<<<row_blocks, 256, 0, stream>>>(eB, eA, sum_io,
                                            rp_pos, pos_col, pos_val,
                                            rp_neg, neg_col, neg_val, 0);
    k_layer<<<row_blocks, 256, 0, stream>>>(eA, eB, sum_io,
                                            rp_pos, pos_col, pos_val,
                                            rp_neg, neg_col, neg_val, 1);
}

// Round 3
// 546.780 us; speedup vs baseline: 1.4284x; 1.2765x over previous
//
#include <hip/hip_runtime.h>

#define NUM_USERS 80000
#define NUM_ITEMS 40000
#define NUM_NODES 120000
#define DIM 64
#define ALPHA_C 0.8f

typedef unsigned short u16;
typedef unsigned int u32;

// fp32 -> bf16 round-nearest-even
__device__ __forceinline__ u16 f2bf(float f) {
    union { float f; u32 i; } v;
    v.f = f;
    u32 i = v.i;
    u32 r = (i + 0x7FFFu + ((i >> 16) & 1u)) >> 16;
    return (u16)r;
}
__device__ __forceinline__ float lo_bf(u32 u) { return __uint_as_float(u << 16); }
__device__ __forceinline__ float hi_bf(u32 u) { return __uint_as_float(u & 0xffff0000u); }

// accumulate 8 bf16 (packed in uint4) * v into acc[8]
__device__ __forceinline__ void acc8(float* __restrict__ acc, float v, uint4 q) {
    const u32* p = (const u32*)&q;
#pragma unroll
    for (int k = 0; k < 4; ++k) {
        u32 u = p[k];
        acc[2 * k]     = fmaf(v, lo_bf(u), acc[2 * k]);
        acc[2 * k + 1] = fmaf(v, hi_bf(u), acc[2 * k + 1]);
    }
}

// ---------------------------------------------------------------------------
// K1: softmax over theta (6 elements) -> theta_w
// ---------------------------------------------------------------------------
__global__ void k_softmax_theta(const float* __restrict__ theta,
                                float* __restrict__ theta_w) {
    if (threadIdx.x == 0 && blockIdx.x == 0) {
        float m = -1e30f;
        for (int i = 0; i < 6; ++i) m = fmaxf(m, theta[i]);
        float e[6];
        float s = 0.f;
        for (int i = 0; i < 6; ++i) { e[i] = expf(theta[i] - m); s += e[i]; }
        for (int i = 0; i < 6; ++i) theta_w[i] = e[i] / s;
    }
}

// ---------------------------------------------------------------------------
// K2: exp_v[e] = exp(dot(p_counts[e, 0:6], theta_w))
// ---------------------------------------------------------------------------
__global__ void k_expv(const float* __restrict__ p_counts,
                       const float* __restrict__ theta_w,
                       float* __restrict__ exp_v, int E) {
    int i = blockIdx.x * blockDim.x + threadIdx.x;
    if (i >= E) return;
    const float* c = p_counts + (size_t)i * 6;
    float v = c[0] * theta_w[0] + c[1] * theta_w[1] + c[2] * theta_w[2] +
              c[3] * theta_w[3] + c[4] * theta_w[4] + c[5] * theta_w[5];
    exp_v[i] = expf(v);
}

// ---------------------------------------------------------------------------
// K3: all three CSR row_ptr arrays in one launch (rows sorted: np.unique)
// ---------------------------------------------------------------------------
__device__ __forceinline__ void lower_bound_ptr(const int* __restrict__ rows,
                                                int nnz, int r,
                                                int* __restrict__ ptr) {
    int lo = 0, hi = nnz;
    while (lo < hi) {
        int mid = (lo + hi) >> 1;
        if (rows[mid] < r) lo = mid + 1; else hi = mid;
    }
    ptr[r] = lo;
}

__global__ void k_row_ptr3(const int* __restrict__ rows_a, int nnz_a, int* __restrict__ pa,
                           const int* __restrict__ rows_b, int nnz_b, int* __restrict__ pb,
                           const int* __restrict__ rows_c, int nnz_c, int* __restrict__ pc) {
    int t = blockIdx.x * blockDim.x + threadIdx.x;
    int which = t / (NUM_NODES + 1);
    int r = t - which * (NUM_NODES + 1);
    if (which == 0) lower_bound_ptr(rows_a, nnz_a, r, pa);
    else if (which == 1) lower_bound_ptr(rows_b, nnz_b, r, pb);
    else if (which == 2) lower_bound_ptr(rows_c, nnz_c, r, pc);
}

// ---------------------------------------------------------------------------
// K4: convert user_emb || item_emb (fp32) -> bf16 table
// ---------------------------------------------------------------------------
__global__ void k_cvt(const float* __restrict__ user_emb,
                      const float* __restrict__ item_emb,
                      u16* __restrict__ emb16) {
    int i = blockIdx.x * blockDim.x + threadIdx.x;   // handles 4 floats
    size_t f = (size_t)i * 4;
    const size_t UTOT = (size_t)NUM_USERS * DIM;
    const size_t TOT = (size_t)NUM_NODES * DIM;
    if (f >= TOT) return;
    float4 v = (f < UTOT) ? *(const float4*)(user_emb + f)
                          : *(const float4*)(item_emb + (f - UTOT));
    ushort4 o;
    o.x = f2bf(v.x); o.y = f2bf(v.y); o.z = f2bf(v.z); o.w = f2bf(v.w);
    *(ushort4*)(emb16 + f) = o;
}

// ---------------------------------------------------------------------------
// Segment gather, 8 lanes/edge, 16B/lane, unroll x2 (no reduction here).
// group = lane>>3 in [0,8), li = lane&7 selects the 16B chunk of the row.
// ---------------------------------------------------------------------------
__device__ __forceinline__ void seg_gather_nr(const int* __restrict__ col,
                                              const float* __restrict__ val,
                                              int start, int end,
                                              const u16* __restrict__ x,
                                              int group, int li,
                                              float* __restrict__ acc) {
    int e = start + group;
    for (; e + 8 < end; e += 16) {
        int c0 = col[e];
        float v0 = val[e];
        int c1 = col[e + 8];
        float v1 = val[e + 8];
        uint4 x0 = *((const uint4*)(x + (size_t)c0 * DIM) + li);
        uint4 x1 = *((const uint4*)(x + (size_t)c1 * DIM) + li);
        acc8(acc, v0, x0);
        acc8(acc, v1, x1);
    }
    if (e < end) {
        int c0 = col[e];
        float v0 = val[e];
        uint4 x0 = *((const uint4*)(x + (size_t)c0 * DIM) + li);
        acc8(acc, v0, x0);
    }
}

__device__ __forceinline__ void reduce8(float* __restrict__ acc) {
#pragma unroll
    for (int m = 8; m < 64; m <<= 1) {
#pragma unroll
        for (int k = 0; k < 8; ++k) acc[k] += __shfl_xor(acc[k], m);
    }
}

// ---------------------------------------------------------------------------
// K5: path SpMM with fused row-softmax. One wave per node/row.
// ---------------------------------------------------------------------------
__global__ void k_path(const u16* __restrict__ emb16,
                       const float* __restrict__ exp_v,
                       const int* __restrict__ rp,
                       const int* __restrict__ cols,
                       u16* __restrict__ e0,
                       float* __restrict__ sum_out) {
    int wid = (blockIdx.x * blockDim.x + threadIdx.x) >> 6;
    if (wid >= NUM_NODES) return;
    int lane = threadIdx.x & 63;
    int group = lane >> 3, li = lane & 7;
    int start = rp[wid], end = rp[wid + 1];

    // softmax denominator over the segment
    float s = 0.f;
    for (int e = start + lane; e < end; e += 64) s += exp_v[e];
#pragma unroll
    for (int m = 1; m < 64; m <<= 1) s += __shfl_xor(s, m);
    float inv = 1.0f / (s + 1e-12f);

    float acc[8];
#pragma unroll
    for (int k = 0; k < 8; ++k) acc[k] = 0.f;

    int e = start + group;
    for (; e + 8 < end; e += 16) {
        int c0 = cols[e];
        float w0 = exp_v[e] * inv;
        int c1 = cols[e + 8];
        float w1 = exp_v[e + 8] * inv;
        uint4 x0 = *((const uint4*)(emb16 + (size_t)c0 * DIM) + li);
        uint4 x1 = *((const uint4*)(emb16 + (size_t)c1 * DIM) + li);
        acc8(acc, w0, x0);
        acc8(acc, w1, x1);
    }
    if (e < end) {
        int c0 = cols[e];
        float w0 = exp_v[e] * inv;
        uint4 x0 = *((const uint4*)(emb16 + (size_t)c0 * DIM) + li);
        acc8(acc, w0, x0);
    }
    reduce8(acc);

    if (lane < 8) {  // lane li owns elements [li*8, li*8+8)
        u32 o[4];
#pragma unroll
        for (int k = 0; k < 4; ++k)
            o[k] = (u32)f2bf(acc[2 * k]) | ((u32)f2bf(acc[2 * k + 1]) << 16);
        *((uint4*)(e0 + (size_t)wid * DIM) + li) = *(uint4*)o;
        float4* sp = (float4*)(sum_out + (size_t)wid * DIM) + li * 2;
        sp[0] = make_float4(acc[0], acc[1], acc[2], acc[3]);
        sp[1] = make_float4(acc[4], acc[5], acc[6], acc[7]);
    }
}

// ---------------------------------------------------------------------------
// K6: one propagation layer. One wave per node/row.
//     res = pos_acc + ALPHA * (e_in[row] - neg_acc)
//     sum_io += res ; final layer: sum_io = (sum_io + res) * 0.25
// ---------------------------------------------------------------------------
__global__ void k_layer(const u16* __restrict__ e_in,
                        u16* __restrict__ e_out,
                        float* __restrict__ sum_io,
                        const int* __restrict__ rp_p,
                        const int* __restrict__ col_p,
                        const float* __restrict__ val_p,
                        const int* __restrict__ rp_n,
                        const int* __restrict__ col_n,
                        const float* __restrict__ val_n,
                        int is_final) {
    int wid = (blockIdx.x * blockDim.x + threadIdx.x) >> 6;
    if (wid >= NUM_NODES) return;
    int lane = threadIdx.x & 63;
    int group = lane >> 3, li = lane & 7;

    float accp[8], accn[8];
#pragma unroll
    for (int k = 0; k < 8; ++k) { accp[k] = 0.f; accn[k] = 0.f; }

    seg_gather_nr(col_p, val_p, rp_p[wid], rp_p[wid + 1], e_in, group, li, accp);
    seg_gather_nr(col_n, val_n, rp_n[wid], rp_n[wid + 1], e_in, group, li, accn);
    reduce8(accp);
    reduce8(accn);

    if (lane < 8) {
        uint4 eq = *((const uint4*)(e_in + (size_t)wid * DIM) + li);
        const u32* ep = (const u32*)&eq;
        float res[8];
#pragma unroll
        for (int k = 0; k < 4; ++k) {
            res[2 * k]     = accp[2 * k]     + ALPHA_C * (lo_bf(ep[k]) - accn[2 * k]);
            res[2 * k + 1] = accp[2 * k + 1] + ALPHA_C * (hi_bf(ep[k]) - accn[2 * k + 1]);
        }
        float4* sp = (float4*)(sum_io + (size_t)wid * DIM) + li * 2;
        float4 s0 = sp[0], s1 = sp[1];
        s0.x += res[0]; s0.y += res[1]; s0.z += res[2]; s0.w += res[3];
        s1.x += res[4]; s1.y += res[5]; s1.z += res[6]; s1.w += res[7];
        if (is_final) {
            s0.x *= 0.25f; s0.y *= 0.25f; s0.z *= 0.25f; s0.w *= 0.25f;
            s1.x *= 0.25f; s1.y *= 0.25f; s1.z *= 0.25f; s1.w *= 0.25f;
        }
        sp[0] = s0; sp[1] = s1;
        if (!is_final) {
            u32 o[4];
#pragma unroll
            for (int k = 0; k < 4; ++k)
                o[k] = (u32)f2bf(res[2 * k]) | ((u32)f2bf(res[2 * k + 1]) << 16);
            *((uint4*)(e_out + (size_t)wid * DIM) + li) = *(uint4*)o;
        }
    }
}

// ---------------------------------------------------------------------------
extern "C" void kernel_launch(void* const* d_in, const int* in_sizes, int n_in,
                              void* d_out, int out_size, void* d_ws, size_t ws_size,
                              hipStream_t stream) {
    const float* user_emb = (const float*)d_in[0];
    const float* item_emb = (const float*)d_in[1];
    const float* theta    = (const float*)d_in[2];
    const int*   pos_row  = (const int*)d_in[3];
    const int*   pos_col  = (const int*)d_in[4];
    const float* pos_val  = (const float*)d_in[5];
    const int*   neg_row  = (const int*)d_in[6];
    const int*   neg_col  = (const int*)d_in[7];
    const float* neg_val  = (const float*)d_in[8];
    const int*   p_row    = (const int*)d_in[9];
    const int*   p_col    = (const int*)d_in[10];
    const float* p_counts = (const float*)d_in[11];
    const int E_pos  = in_sizes[3];
    const int E_neg  = in_sizes[6];
    const int E_path = in_sizes[9];

    // bump allocator over d_ws (256B aligned chunks)
    char* wsb = (char*)d_ws;
    size_t off = 0;
    auto alloc = [&](size_t bytes) -> void* {
        void* p = wsb + off;
        off = (off + bytes + 255) & ~(size_t)255;
        return p;
    };
    float* theta_w = (float*)alloc(6 * sizeof(float));
    float* exp_v   = (float*)alloc((size_t)E_path * sizeof(float));
    int*   rp_pos  = (int*)alloc((size_t)(NUM_NODES + 1) * sizeof(int));
    int*   rp_neg  = (int*)alloc((size_t)(NUM_NODES + 1) * sizeof(int));
    int*   rp_path = (int*)alloc((size_t)(NUM_NODES + 1) * sizeof(int));
    u16*   emb16   = (u16*)alloc((size_t)NUM_NODES * DIM * sizeof(u16));
    u16*   eA      = (u16*)alloc((size_t)NUM_NODES * DIM * sizeof(u16));
    u16*   eB      = (u16*)alloc((size_t)NUM_NODES * DIM * sizeof(u16));
    float* sum_io  = (float*)d_out;  // running sum accumulates directly in d_out

    k_softmax_theta<<<1, 64, 0, stream>>>(theta, theta_w);
    k_expv<<<(E_path + 255) / 256, 256, 0, stream>>>(p_counts, theta_w, exp_v, E_path);

    int total_rp = 3 * (NUM_NODES + 1);
    k_row_ptr3<<<(total_rp + 255) / 256, 256, 0, stream>>>(
        pos_row, E_pos, rp_pos, neg_row, E_neg, rp_neg, p_row, E_path, rp_path);

    int cvt_threads = (NUM_NODES * DIM) / 4;
    k_cvt<<<(cvt_threads + 255) / 256, 256, 0, stream>>>(user_emb, item_emb, emb16);

    // one wave per node, 4 waves (256 threads) per block
    int row_blocks = NUM_NODES / 4;  // 120000 / 4 = 30000

    k_path<<<row_blocks, 256, 0, stream>>>(emb16, exp_v, rp_path, p_col, eA, sum_io);
    k_layer<<<row_blocks, 256, 0, stream>>>(eA, eB, sum_io,
                                            rp_pos, pos_col, pos_val,
                                            rp_neg, neg_col, neg_val, 0);
    k_layer<<<row_blocks, 256, 0, stream>>>(eB, eA, sum_io,
                                            rp_pos, pos_col, pos_val,
                                            rp_neg, neg_col, neg_val, 0);
    k_layer<<<row_blocks, 256, 0, stream>>>(eA, eB, sum_io,
                                            rp_pos, pos_col, pos_val,
                                            rp_neg, neg_col, neg_val, 1);
}

// Round 4
// 497.171 us; speedup vs baseline: 1.5709x; 1.0998x over previous
//
#include <hip/hip_runtime.h>

#define NUM_USERS 80000
#define NUM_ITEMS 40000
#define NUM_NODES 120000
#define DIM 64
#define ALPHA_C 0.8f

typedef unsigned short u16;
typedef unsigned int u32;

// fp32 -> bf16 round-nearest-even
__device__ __forceinline__ u16 f2bf(float f) {
    union { float f; u32 i; } v;
    v.f = f;
    u32 i = v.i;
    u32 r = (i + 0x7FFFu + ((i >> 16) & 1u)) >> 16;
    return (u16)r;
}
__device__ __forceinline__ float lo_bf(u32 u) { return __uint_as_float(u << 16); }
__device__ __forceinline__ float hi_bf(u32 u) { return __uint_as_float(u & 0xffff0000u); }

// accumulate 8 bf16 (packed in uint4) * v into acc[8]
__device__ __forceinline__ void acc8(float* __restrict__ acc, float v, uint4 q) {
    const u32* p = (const u32*)&q;
#pragma unroll
    for (int k = 0; k < 4; ++k) {
        u32 u = p[k];
        acc[2 * k]     = fmaf(v, lo_bf(u), acc[2 * k]);
        acc[2 * k + 1] = fmaf(v, hi_bf(u), acc[2 * k + 1]);
    }
}

// ---------------------------------------------------------------------------
// K1: softmax over theta (6 elements) -> theta_w
// ---------------------------------------------------------------------------
__global__ void k_softmax_theta(const float* __restrict__ theta,
                                float* __restrict__ theta_w) {
    if (threadIdx.x == 0 && blockIdx.x == 0) {
        float m = -1e30f;
        for (int i = 0; i < 6; ++i) m = fmaxf(m, theta[i]);
        float e[6];
        float s = 0.f;
        for (int i = 0; i < 6; ++i) { e[i] = expf(theta[i] - m); s += e[i]; }
        for (int i = 0; i < 6; ++i) theta_w[i] = e[i] / s;
    }
}

// ---------------------------------------------------------------------------
// K2: exp_v[e] = exp(dot(p_counts[e, 0:6], theta_w))
// ---------------------------------------------------------------------------
__global__ void k_expv(const float* __restrict__ p_counts,
                       const float* __restrict__ theta_w,
                       float* __restrict__ exp_v, int E) {
    int i = blockIdx.x * blockDim.x + threadIdx.x;
    if (i >= E) return;
    const float* c = p_counts + (size_t)i * 6;
    float v = c[0] * theta_w[0] + c[1] * theta_w[1] + c[2] * theta_w[2] +
              c[3] * theta_w[3] + c[4] * theta_w[4] + c[5] * theta_w[5];
    exp_v[i] = expf(v);
}

// ---------------------------------------------------------------------------
// K3: all three CSR row_ptr arrays in one launch (rows sorted: np.unique)
// ---------------------------------------------------------------------------
__device__ __forceinline__ void lower_bound_ptr(const int* __restrict__ rows,
                                                int nnz, int r,
                                                int* __restrict__ ptr) {
    int lo = 0, hi = nnz;
    while (lo < hi) {
        int mid = (lo + hi) >> 1;
        if (rows[mid] < r) lo = mid + 1; else hi = mid;
    }
    ptr[r] = lo;
}

__global__ void k_row_ptr3(const int* __restrict__ rows_a, int nnz_a, int* __restrict__ pa,
                           const int* __restrict__ rows_b, int nnz_b, int* __restrict__ pb,
                           const int* __restrict__ rows_c, int nnz_c, int* __restrict__ pc) {
    int t = blockIdx.x * blockDim.x + threadIdx.x;
    int which = t / (NUM_NODES + 1);
    int r = t - which * (NUM_NODES + 1);
    if (which == 0) lower_bound_ptr(rows_a, nnz_a, r, pa);
    else if (which == 1) lower_bound_ptr(rows_b, nnz_b, r, pb);
    else if (which == 2) lower_bound_ptr(rows_c, nnz_c, r, pc);
}

// ---------------------------------------------------------------------------
// K4: convert user_emb || item_emb (fp32) -> bf16 table
// ---------------------------------------------------------------------------
__global__ void k_cvt(const float* __restrict__ user_emb,
                      const float* __restrict__ item_emb,
                      u16* __restrict__ emb16) {
    int i = blockIdx.x * blockDim.x + threadIdx.x;   // handles 4 floats
    size_t f = (size_t)i * 4;
    const size_t UTOT = (size_t)NUM_USERS * DIM;
    const size_t TOT = (size_t)NUM_NODES * DIM;
    if (f >= TOT) return;
    float4 v = (f < UTOT) ? *(const float4*)(user_emb + f)
                          : *(const float4*)(item_emb + (f - UTOT));
    ushort4 o;
    o.x = f2bf(v.x); o.y = f2bf(v.y); o.z = f2bf(v.z); o.w = f2bf(v.w);
    *(ushort4*)(emb16 + f) = o;
}

// ---------------------------------------------------------------------------
// Group-serial segment gather: an 8-lane group walks its whole segment.
// Lane li (0..7) owns elements [8*li, 8*li+8) of the 64-dim row (uint4 load).
// No cross-group reduction needed. Unroll x2 for MLP.
// ---------------------------------------------------------------------------
__device__ __forceinline__ void seg_gather_grp(const int* __restrict__ col,
                                               const float* __restrict__ val,
                                               int start, int end,
                                               const u16* __restrict__ x,
                                               int li,
                                               float* __restrict__ acc) {
    int e = start;
    for (; e + 1 < end; e += 2) {
        int c0 = col[e];
        float v0 = val[e];
        int c1 = col[e + 1];
        float v1 = val[e + 1];
        uint4 x0 = *((const uint4*)(x + (size_t)c0 * DIM) + li);
        uint4 x1 = *((const uint4*)(x + (size_t)c1 * DIM) + li);
        acc8(acc, v0, x0);
        acc8(acc, v1, x1);
    }
    if (e < end) {
        int c0 = col[e];
        float v0 = val[e];
        uint4 x0 = *((const uint4*)(x + (size_t)c0 * DIM) + li);
        acc8(acc, v0, x0);
    }
}

// ---------------------------------------------------------------------------
// K5: path SpMM with fused row-softmax. One 8-lane group per row.
// ---------------------------------------------------------------------------
__global__ void k_path(const u16* __restrict__ emb16,
                       const float* __restrict__ exp_v,
                       const int* __restrict__ rp,
                       const int* __restrict__ cols,
                       u16* __restrict__ e0,
                       float* __restrict__ sum_out) {
    int t = blockIdx.x * blockDim.x + threadIdx.x;
    int row = t >> 3;            // one 8-lane group per row
    if (row >= NUM_NODES) return;
    int li = threadIdx.x & 7;
    int start = rp[row], end = rp[row + 1];

    // softmax denominator over the segment (8-lane strided + group reduce)
    float s = 0.f;
    for (int e = start + li; e < end; e += 8) s += exp_v[e];
    s += __shfl_xor(s, 1);
    s += __shfl_xor(s, 2);
    s += __shfl_xor(s, 4);
    float inv = 1.0f / (s + 1e-12f);

    float acc[8];
#pragma unroll
    for (int k = 0; k < 8; ++k) acc[k] = 0.f;

    int e = start;
    for (; e + 1 < end; e += 2) {
        int c0 = cols[e];
        float w0 = exp_v[e] * inv;
        int c1 = cols[e + 1];
        float w1 = exp_v[e + 1] * inv;
        uint4 x0 = *((const uint4*)(emb16 + (size_t)c0 * DIM) + li);
        uint4 x1 = *((const uint4*)(emb16 + (size_t)c1 * DIM) + li);
        acc8(acc, w0, x0);
        acc8(acc, w1, x1);
    }
    if (e < end) {
        int c0 = cols[e];
        float w0 = exp_v[e] * inv;
        uint4 x0 = *((const uint4*)(emb16 + (size_t)c0 * DIM) + li);
        acc8(acc, w0, x0);
    }

    // lane li owns elements [8*li, 8*li+8)
    u32 o[4];
#pragma unroll
    for (int k = 0; k < 4; ++k)
        o[k] = (u32)f2bf(acc[2 * k]) | ((u32)f2bf(acc[2 * k + 1]) << 16);
    *((uint4*)(e0 + (size_t)row * DIM) + li) = *(uint4*)o;
    float4* sp = (float4*)(sum_out + (size_t)row * DIM) + li * 2;
    sp[0] = make_float4(acc[0], acc[1], acc[2], acc[3]);
    sp[1] = make_float4(acc[4], acc[5], acc[6], acc[7]);
}

// ---------------------------------------------------------------------------
// K6: one propagation layer. One 8-lane group per row.
//     res = pos_acc + ALPHA * (e_in[row] - neg_acc)
//     sum_io += res ; final layer: sum_io = (sum_io + res) * 0.25
// ---------------------------------------------------------------------------
__global__ void k_layer(const u16* __restrict__ e_in,
                        u16* __restrict__ e_out,
                        float* __restrict__ sum_io,
                        const int* __restrict__ rp_p,
                        const int* __restrict__ col_p,
                        const float* __restrict__ val_p,
                        const int* __restrict__ rp_n,
                        const int* __restrict__ col_n,
                        const float* __restrict__ val_n,
                        int is_final) {
    int t = blockIdx.x * blockDim.x + threadIdx.x;
    int row = t >> 3;            // one 8-lane group per row
    if (row >= NUM_NODES) return;
    int li = threadIdx.x & 7;

    float accp[8], accn[8];
#pragma unroll
    for (int k = 0; k < 8; ++k) { accp[k] = 0.f; accn[k] = 0.f; }

    seg_gather_grp(col_p, val_p, rp_p[row], rp_p[row + 1], e_in, li, accp);
    seg_gather_grp(col_n, val_n, rp_n[row], rp_n[row + 1], e_in, li, accn);

    uint4 eq = *((const uint4*)(e_in + (size_t)row * DIM) + li);
    const u32* ep = (const u32*)&eq;
    float res[8];
#pragma unroll
    for (int k = 0; k < 4; ++k) {
        res[2 * k]     = accp[2 * k]     + ALPHA_C * (lo_bf(ep[k]) - accn[2 * k]);
        res[2 * k + 1] = accp[2 * k + 1] + ALPHA_C * (hi_bf(ep[k]) - accn[2 * k + 1]);
    }
    float4* sp = (float4*)(sum_io + (size_t)row * DIM) + li * 2;
    float4 s0 = sp[0], s1 = sp[1];
    s0.x += res[0]; s0.y += res[1]; s0.z += res[2]; s0.w += res[3];
    s1.x += res[4]; s1.y += res[5]; s1.z += res[6]; s1.w += res[7];
    if (is_final) {
        s0.x *= 0.25f; s0.y *= 0.25f; s0.z *= 0.25f; s0.w *= 0.25f;
        s1.x *= 0.25f; s1.y *= 0.25f; s1.z *= 0.25f; s1.w *= 0.25f;
    }
    sp[0] = s0; sp[1] = s1;
    if (!is_final) {
        u32 o[4];
#pragma unroll
        for (int k = 0; k < 4; ++k)
            o[k] = (u32)f2bf(res[2 * k]) | ((u32)f2bf(res[2 * k + 1]) << 16);
        *((uint4*)(e_out + (size_t)row * DIM) + li) = *(uint4*)o;
    }
}

// ---------------------------------------------------------------------------
extern "C" void kernel_launch(void* const* d_in, const int* in_sizes, int n_in,
                              void* d_out, int out_size, void* d_ws, size_t ws_size,
                              hipStream_t stream) {
    const float* user_emb = (const float*)d_in[0];
    const float* item_emb = (const float*)d_in[1];
    const float* theta    = (const float*)d_in[2];
    const int*   pos_row  = (const int*)d_in[3];
    const int*   pos_col  = (const int*)d_in[4];
    const float* pos_val  = (const float*)d_in[5];
    const int*   neg_row  = (const int*)d_in[6];
    const int*   neg_col  = (const int*)d_in[7];
    const float* neg_val  = (const float*)d_in[8];
    const int*   p_row    = (const int*)d_in[9];
    const int*   p_col    = (const int*)d_in[10];
    const float* p_counts = (const float*)d_in[11];
    const int E_pos  = in_sizes[3];
    const int E_neg  = in_sizes[6];
    const int E_path = in_sizes[9];

    // bump allocator over d_ws (256B aligned chunks)
    char* wsb = (char*)d_ws;
    size_t off = 0;
    auto alloc = [&](size_t bytes) -> void* {
        void* p = wsb + off;
        off = (off + bytes + 255) & ~(size_t)255;
        return p;
    };
    float* theta_w = (float*)alloc(6 * sizeof(float));
    float* exp_v   = (float*)alloc((size_t)E_path * sizeof(float));
    int*   rp_pos  = (int*)alloc((size_t)(NUM_NODES + 1) * sizeof(int));
    int*   rp_neg  = (int*)alloc((size_t)(NUM_NODES + 1) * sizeof(int));
    int*   rp_path = (int*)alloc((size_t)(NUM_NODES + 1) * sizeof(int));
    u16*   emb16   = (u16*)alloc((size_t)NUM_NODES * DIM * sizeof(u16));
    u16*   eA      = (u16*)alloc((size_t)NUM_NODES * DIM * sizeof(u16));
    u16*   eB      = (u16*)alloc((size_t)NUM_NODES * DIM * sizeof(u16));
    float* sum_io  = (float*)d_out;  // running sum accumulates directly in d_out

    k_softmax_theta<<<1, 64, 0, stream>>>(theta, theta_w);
    k_expv<<<(E_path + 255) / 256, 256, 0, stream>>>(p_counts, theta_w, exp_v, E_path);

    int total_rp = 3 * (NUM_NODES + 1);
    k_row_ptr3<<<(total_rp + 255) / 256, 256, 0, stream>>>(
        pos_row, E_pos, rp_pos, neg_row, E_neg, rp_neg, p_row, E_path, rp_path);

    int cvt_threads = (NUM_NODES * DIM) / 4;
    k_cvt<<<(cvt_threads + 255) / 256, 256, 0, stream>>>(user_emb, item_emb, emb16);

    // one 8-lane group per row: 32 rows per 256-thread block
    int row_blocks = (NUM_NODES + 31) / 32;  // 3750

    k_path<<<row_blocks, 256, 0, stream>>>(emb16, exp_v, rp_path, p_col, eA, sum_io);
    k_layer<<<row_blocks, 256, 0, stream>>>(eA, eB, sum_io,
                                            rp_pos, pos_col, pos_val,
                                            rp_neg, neg_col, neg_val, 0);
    k_layer<<<row_blocks, 256, 0, stream>>>(eB, eA, sum_io,
                                            rp_pos, pos_col, pos_val,
                                            rp_neg, neg_col, neg_val, 0);
    k_layer<<<row_blocks, 256, 0, stream>>>(eA, eB, sum_io,
                                            rp_pos, pos_col, pos_val,
                                            rp_neg, neg_col, neg_val, 1);
}

// Round 5
// 477.706 us; speedup vs baseline: 1.6349x; 1.0407x over previous
//
#include <hip/hip_runtime.h>

#define NUM_USERS 80000
#define NUM_ITEMS 40000
#define NUM_NODES 120000
#define DIM 64
#define ALPHA_C 0.8f

typedef unsigned short u16;
typedef unsigned int u32;

// fp32 -> bf16 round-nearest-even
__device__ __forceinline__ u16 f2bf(float f) {
    union { float f; u32 i; } v;
    v.f = f;
    u32 i = v.i;
    u32 r = (i + 0x7FFFu + ((i >> 16) & 1u)) >> 16;
    return (u16)r;
}
__device__ __forceinline__ float lo_bf(u32 u) { return __uint_as_float(u << 16); }
__device__ __forceinline__ float hi_bf(u32 u) { return __uint_as_float(u & 0xffff0000u); }

// accumulate 8 bf16 (packed in uint4) * v into acc[8]
__device__ __forceinline__ void acc8(float* __restrict__ acc, float v, uint4 q) {
    const u32* p = (const u32*)&q;
#pragma unroll
    for (int k = 0; k < 4; ++k) {
        u32 u = p[k];
        acc[2 * k]     = fmaf(v, lo_bf(u), acc[2 * k]);
        acc[2 * k + 1] = fmaf(v, hi_bf(u), acc[2 * k + 1]);
    }
}

__device__ __forceinline__ uint4 ldrow(const u16* __restrict__ x, int c, int li) {
    return *((const uint4*)(x + (size_t)c * DIM) + li);
}

// ---------------------------------------------------------------------------
// Software-pipelined segment gather (8-lane group walks its whole segment).
// 2-stage prefetch of col/val (addresses never stall) + 1-stage prefetch of
// row gathers (FMAs consume the previous pair while current pair in flight).
// Lane li (0..7) owns elements [8*li, 8*li+8) of the 64-dim row.
// ---------------------------------------------------------------------------
__device__ __forceinline__ void seg_pipe(const int* __restrict__ col,
                                         const float* __restrict__ val,
                                         int start, int end,
                                         const u16* __restrict__ x,
                                         int li, float* __restrict__ acc) {
    int n = end - start;
    const int* cp = col + start;
    const float* vp = val + start;
    int np = n >> 1;
    if (np >= 2) {
        int   ca0 = cp[0], ca1 = cp[1];
        float va0 = vp[0], va1 = vp[1];
        int   cb0 = cp[2], cb1 = cp[3];
        float vb0 = vp[2], vb1 = vp[3];
        uint4 xa0 = ldrow(x, ca0, li);
        uint4 xa1 = ldrow(x, ca1, li);
        for (int p = 2; p < np; ++p) {
            int   cc0 = cp[2 * p],     cc1 = cp[2 * p + 1];
            float vc0 = vp[2 * p],     vc1 = vp[2 * p + 1];
            uint4 xb0 = ldrow(x, cb0, li);
            uint4 xb1 = ldrow(x, cb1, li);
            acc8(acc, va0, xa0);
            acc8(acc, va1, xa1);
            va0 = vb0; va1 = vb1; xa0 = xb0; xa1 = xb1;
            cb0 = cc0; cb1 = cc1; vb0 = vc0; vb1 = vc1;
        }
        uint4 xb0 = ldrow(x, cb0, li);
        uint4 xb1 = ldrow(x, cb1, li);
        acc8(acc, va0, xa0);
        acc8(acc, va1, xa1);
        acc8(acc, vb0, xb0);
        acc8(acc, vb1, xb1);
        if (n & 1) {
            int c = cp[n - 1];
            float v = vp[n - 1];
            uint4 xq = ldrow(x, c, li);
            acc8(acc, v, xq);
        }
    } else {
        for (int e = 0; e < n; ++e) {
            int c = cp[e];
            float v = vp[e];
            uint4 xq = ldrow(x, c, li);
            acc8(acc, v, xq);
        }
    }
}

// ---------------------------------------------------------------------------
// K1: softmax over theta (6 elements) -> theta_w
// ---------------------------------------------------------------------------
__global__ void k_softmax_theta(const float* __restrict__ theta,
                                float* __restrict__ theta_w) {
    if (threadIdx.x == 0 && blockIdx.x == 0) {
        float m = -1e30f;
        for (int i = 0; i < 6; ++i) m = fmaxf(m, theta[i]);
        float e[6];
        float s = 0.f;
        for (int i = 0; i < 6; ++i) { e[i] = expf(theta[i] - m); s += e[i]; }
        for (int i = 0; i < 6; ++i) theta_w[i] = e[i] / s;
    }
}

// ---------------------------------------------------------------------------
// K2: exp_v[e] = exp(dot(p_counts[e, 0:6], theta_w))
// ---------------------------------------------------------------------------
__global__ void k_expv(const float* __restrict__ p_counts,
                       const float* __restrict__ theta_w,
                       float* __restrict__ exp_v, int E) {
    int i = blockIdx.x * blockDim.x + threadIdx.x;
    if (i >= E) return;
    const float* c = p_counts + (size_t)i * 6;
    float v = c[0] * theta_w[0] + c[1] * theta_w[1] + c[2] * theta_w[2] +
              c[3] * theta_w[3] + c[4] * theta_w[4] + c[5] * theta_w[5];
    exp_v[i] = expf(v);
}

// ---------------------------------------------------------------------------
// K3: all three CSR row_ptr arrays in one launch (rows sorted: np.unique)
// ---------------------------------------------------------------------------
__device__ __forceinline__ void lower_bound_ptr(const int* __restrict__ rows,
                                                int nnz, int r,
                                                int* __restrict__ ptr) {
    int lo = 0, hi = nnz;
    while (lo < hi) {
        int mid = (lo + hi) >> 1;
        if (rows[mid] < r) lo = mid + 1; else hi = mid;
    }
    ptr[r] = lo;
}

__global__ void k_row_ptr3(const int* __restrict__ rows_a, int nnz_a, int* __restrict__ pa,
                           const int* __restrict__ rows_b, int nnz_b, int* __restrict__ pb,
                           const int* __restrict__ rows_c, int nnz_c, int* __restrict__ pc) {
    int t = blockIdx.x * blockDim.x + threadIdx.x;
    int which = t / (NUM_NODES + 1);
    int r = t - which * (NUM_NODES + 1);
    if (which == 0) lower_bound_ptr(rows_a, nnz_a, r, pa);
    else if (which == 1) lower_bound_ptr(rows_b, nnz_b, r, pb);
    else if (which == 2) lower_bound_ptr(rows_c, nnz_c, r, pc);
}

// ---------------------------------------------------------------------------
// K4: convert user_emb || item_emb (fp32) -> bf16 table
// ---------------------------------------------------------------------------
__global__ void k_cvt(const float* __restrict__ user_emb,
                      const float* __restrict__ item_emb,
                      u16* __restrict__ emb16) {
    int i = blockIdx.x * blockDim.x + threadIdx.x;   // handles 4 floats
    size_t f = (size_t)i * 4;
    const size_t UTOT = (size_t)NUM_USERS * DIM;
    const size_t TOT = (size_t)NUM_NODES * DIM;
    if (f >= TOT) return;
    float4 v = (f < UTOT) ? *(const float4*)(user_emb + f)
                          : *(const float4*)(item_emb + (f - UTOT));
    ushort4 o;
    o.x = f2bf(v.x); o.y = f2bf(v.y); o.z = f2bf(v.z); o.w = f2bf(v.w);
    *(ushort4*)(emb16 + f) = o;
}

// ---------------------------------------------------------------------------
// K5: path SpMM with fused row-softmax. One 8-lane group per row.
//     acc = sum_e exp_v[e] * x[col[e]]; result = acc * inv  (weights linear)
// ---------------------------------------------------------------------------
__global__ void k_path(const u16* __restrict__ emb16,
                       const float* __restrict__ exp_v,
                       const int* __restrict__ rp,
                       const int* __restrict__ cols,
                       u16* __restrict__ e0,
                       float* __restrict__ sum_out) {
    int t = blockIdx.x * blockDim.x + threadIdx.x;
    int row = t >> 3;            // one 8-lane group per row
    if (row >= NUM_NODES) return;
    int li = threadIdx.x & 7;
    int start = rp[row], end = rp[row + 1];

    // softmax denominator over the segment (8-lane strided + group reduce)
    float s = 0.f;
    for (int e = start + li; e < end; e += 8) s += exp_v[e];
    s += __shfl_xor(s, 1);
    s += __shfl_xor(s, 2);
    s += __shfl_xor(s, 4);
    float inv = 1.0f / (s + 1e-12f);

    float acc[8];
#pragma unroll
    for (int k = 0; k < 8; ++k) acc[k] = 0.f;

    seg_pipe(cols, exp_v, start, end, emb16, li, acc);

#pragma unroll
    for (int k = 0; k < 8; ++k) acc[k] *= inv;

    // lane li owns elements [8*li, 8*li+8)
    u32 o[4];
#pragma unroll
    for (int k = 0; k < 4; ++k)
        o[k] = (u32)f2bf(acc[2 * k]) | ((u32)f2bf(acc[2 * k + 1]) << 16);
    *((uint4*)(e0 + (size_t)row * DIM) + li) = *(uint4*)o;
    float4* sp = (float4*)(sum_out + (size_t)row * DIM) + li * 2;
    sp[0] = make_float4(acc[0], acc[1], acc[2], acc[3]);
    sp[1] = make_float4(acc[4], acc[5], acc[6], acc[7]);
}

// ---------------------------------------------------------------------------
// K6: one propagation layer. One 8-lane group per row.
//     res = pos_acc + ALPHA * (e_in[row] - neg_acc)
//     sum_io += res ; final layer: sum_io = (sum_io + res) * 0.25
// ---------------------------------------------------------------------------
__global__ void k_layer(const u16* __restrict__ e_in,
                        u16* __restrict__ e_out,
                        float* __restrict__ sum_io,
                        const int* __restrict__ rp_p,
                        const int* __restrict__ col_p,
                        const float* __restrict__ val_p,
                        const int* __restrict__ rp_n,
                        const int* __restrict__ col_n,
                        const float* __restrict__ val_n,
                        int is_final) {
    int t = blockIdx.x * blockDim.x + threadIdx.x;
    int row = t >> 3;            // one 8-lane group per row
    if (row >= NUM_NODES) return;
    int li = threadIdx.x & 7;

    float accp[8], accn[8];
#pragma unroll
    for (int k = 0; k < 8; ++k) { accp[k] = 0.f; accn[k] = 0.f; }

    seg_pipe(col_p, val_p, rp_p[row], rp_p[row + 1], e_in, li, accp);
    seg_pipe(col_n, val_n, rp_n[row], rp_n[row + 1], e_in, li, accn);

    uint4 eq = *((const uint4*)(e_in + (size_t)row * DIM) + li);
    const u32* ep = (const u32*)&eq;
    float res[8];
#pragma unroll
    for (int k = 0; k < 4; ++k) {
        res[2 * k]     = accp[2 * k]     + ALPHA_C * (lo_bf(ep[k]) - accn[2 * k]);
        res[2 * k + 1] = accp[2 * k + 1] + ALPHA_C * (hi_bf(ep[k]) - accn[2 * k + 1]);
    }
    float4* sp = (float4*)(sum_io + (size_t)row * DIM) + li * 2;
    float4 s0 = sp[0], s1 = sp[1];
    s0.x += res[0]; s0.y += res[1]; s0.z += res[2]; s0.w += res[3];
    s1.x += res[4]; s1.y += res[5]; s1.z += res[6]; s1.w += res[7];
    if (is_final) {
        s0.x *= 0.25f; s0.y *= 0.25f; s0.z *= 0.25f; s0.w *= 0.25f;
        s1.x *= 0.25f; s1.y *= 0.25f; s1.z *= 0.25f; s1.w *= 0.25f;
    }
    sp[0] = s0; sp[1] = s1;
    if (!is_final) {
        u32 o[4];
#pragma unroll
        for (int k = 0; k < 4; ++k)
            o[k] = (u32)f2bf(res[2 * k]) | ((u32)f2bf(res[2 * k + 1]) << 16);
        *((uint4*)(e_out + (size_t)row * DIM) + li) = *(uint4*)o;
    }
}

// ---------------------------------------------------------------------------
extern "C" void kernel_launch(void* const* d_in, const int* in_sizes, int n_in,
                              void* d_out, int out_size, void* d_ws, size_t ws_size,
                              hipStream_t stream) {
    const float* user_emb = (const float*)d_in[0];
    const float* item_emb = (const float*)d_in[1];
    const float* theta    = (const float*)d_in[2];
    const int*   pos_row  = (const int*)d_in[3];
    const int*   pos_col  = (const int*)d_in[4];
    const float* pos_val  = (const float*)d_in[5];
    const int*   neg_row  = (const int*)d_in[6];
    const int*   neg_col  = (const int*)d_in[7];
    const float* neg_val  = (const float*)d_in[8];
    const int*   p_row    = (const int*)d_in[9];
    const int*   p_col    = (const int*)d_in[10];
    const float* p_counts = (const float*)d_in[11];
    const int E_pos  = in_sizes[3];
    const int E_neg  = in_sizes[6];
    const int E_path = in_sizes[9];

    // bump allocator over d_ws (256B aligned chunks)
    char* wsb = (char*)d_ws;
    size_t off = 0;
    auto alloc = [&](size_t bytes) -> void* {
        void* p = wsb + off;
        off = (off + bytes + 255) & ~(size_t)255;
        return p;
    };
    float* theta_w = (float*)alloc(6 * sizeof(float));
    float* exp_v   = (float*)alloc((size_t)E_path * sizeof(float));
    int*   rp_pos  = (int*)alloc((size_t)(NUM_NODES + 1) * sizeof(int));
    int*   rp_neg  = (int*)alloc((size_t)(NUM_NODES + 1) * sizeof(int));
    int*   rp_path = (int*)alloc((size_t)(NUM_NODES + 1) * sizeof(int));
    u16*   emb16   = (u16*)alloc((size_t)NUM_NODES * DIM * sizeof(u16));
    u16*   eA      = (u16*)alloc((size_t)NUM_NODES * DIM * sizeof(u16));
    u16*   eB      = (u16*)alloc((size_t)NUM_NODES * DIM * sizeof(u16));
    float* sum_io  = (float*)d_out;  // running sum accumulates directly in d_out

    k_softmax_theta<<<1, 64, 0, stream>>>(theta, theta_w);
    k_expv<<<(E_path + 255) / 256, 256, 0, stream>>>(p_counts, theta_w, exp_v, E_path);

    int total_rp = 3 * (NUM_NODES + 1);
    k_row_ptr3<<<(total_rp + 255) / 256, 256, 0, stream>>>(
        pos_row, E_pos, rp_pos, neg_row, E_neg, rp_neg, p_row, E_path, rp_path);

    int cvt_threads = (NUM_NODES * DIM) / 4;
    k_cvt<<<(cvt_threads + 255) / 256, 256, 0, stream>>>(user_emb, item_emb, emb16);

    // one 8-lane group per row: 32 rows per 256-thread block
    int row_blocks = (NUM_NODES + 31) / 32;  // 3750

    k_path<<<row_blocks, 256, 0, stream>>>(emb16, exp_v, rp_path, p_col, eA, sum_io);
    k_layer<<<row_blocks, 256, 0, stream>>>(eA, eB, sum_io,
                                            rp_pos, pos_col, pos_val,
                                            rp_neg, neg_col, neg_val, 0);
    k_layer<<<row_blocks, 256, 0, stream>>>(eB, eA, sum_io,
                                            rp_pos, pos_col, pos_val,
                                            rp_neg, neg_col, neg_val, 0);
    k_layer<<<row_blocks, 256, 0, stream>>>(eA, eB, sum_io,
                                            rp_pos, pos_col, pos_val,
                                            rp_neg, neg_col, neg_val, 1);
}